// Round 1
// baseline (439.019 us; speedup 1.0000x reference)
//
#include <hip/hip_runtime.h>

#define DEVINL __device__ __forceinline__

typedef __attribute__((ext_vector_type(8))) __bf16 bf16x8;
typedef __attribute__((ext_vector_type(4))) __bf16 bf16x4;
typedef __attribute__((ext_vector_type(4))) float f32x4;

// D = A(16x32) * B(32x16) + C, bf16 inputs, fp32 accum.
// A: m=lane&15, k=(lane>>4)*8+j ; B: n=lane&15, k=(lane>>4)*8+j
// C/D: col=lane&15, row=(lane>>4)*4+reg   [m89/m120-verified]
DEVINL f32x4 mfma16(bf16x8 a, bf16x8 b, f32x4 c) {
  return __builtin_amdgcn_mfma_f32_16x16x32_bf16(a, b, c, 0, 0, 0);
}

// Fragment of W^T: value[j] = W[kb+j][n]  (W stored (in,out), row-major 128x128)
DEVINL bf16x8 loadWfrag(const float* __restrict__ W, int kb, int n) {
  bf16x8 f;
#pragma unroll
  for (int j = 0; j < 8; ++j) f[j] = (__bf16)W[(kb + j) * 128 + n];
  return f;
}

// ---------------------------------------------------------------------------
// Kernel A: per (seq, 256-token chunk): K,V projections (bf16 MFMA), elu+1 on
// K; K^T,V^T -> LDS (wave-private rows); KtV (per-head 32x32) + ksum
// accumulated, atomicAdd to ws.  Q is NOT computed here (kernel B recomputes
// it from X, which stays L3-resident) -- saves 67MB write + 67MB read.
// Grid 1024 -> 3 blocks/CU (LDS 3*54272=162816 <= 163840); X staging is
// register-double-buffered so next tile's loads fly during compute.
// ---------------------------------------------------------------------------
__global__ __launch_bounds__(256, 3)
void kv_ktv_kernel(const float* __restrict__ X,
                   const float* __restrict__ Wk, const float* __restrict__ bk,
                   const float* __restrict__ Wv, const float* __restrict__ bv,
                   float* __restrict__ ktvWs, float* __restrict__ ksumWs)
{
  __shared__ __bf16 Xs[64 * 136];   // [tok][e], pad 8 -> 2-way bank alias only
  __shared__ __bf16 Kt[128 * 72];   // [e][tok] (transposed), pad 8
  __shared__ __bf16 Vt[128 * 72];

  const int tid  = threadIdx.x;
  const int lane = tid & 63;
  const int w    = tid >> 6;       // wave 0..3 (= head for KtV)
  const int l15  = lane & 15;
  const int quad = lane >> 4;      // 0..3
  const int s     = blockIdx.x >> 3;   // sequence 0..127
  const int chunk = blockIdx.x & 7;    // 256-token chunk
  const float* Xc = X + ((size_t)s * 2048 + chunk * 256) * 128;

  // Prefetch tile 0 into registers FIRST so it overlaps the weight preamble.
  float4 xst[8];
#pragma unroll
  for (int i = 0; i < 8; ++i) {
    const int flat = tid + i * 256;
    xst[i] = *(const float4*)(Xc + (flat >> 5) * 128 + (flat & 31) * 4);
  }

  // Register-resident weight fragments. Wave w owns out-dims [32w, 32w+32).
  bf16x8 wkF[2][4], wvF[2][4];
#pragma unroll
  for (int nt = 0; nt < 2; ++nt) {
    const int n = w * 32 + nt * 16 + l15;
#pragma unroll
    for (int kk = 0; kk < 4; ++kk) {
      const int kb = kk * 32 + quad * 8;
      wkF[nt][kk] = loadWfrag(Wk, kb, n);
      wvF[nt][kk] = loadWfrag(Wv, kb, n);
    }
  }
  float bkr[2], bvr[2];
#pragma unroll
  for (int nt = 0; nt < 2; ++nt) {
    bkr[nt] = bk[w * 32 + nt * 16 + l15];
    bvr[nt] = bv[w * 32 + nt * 16 + l15];
  }

  f32x4 accT[2][2] = {};          // per-head KtV accumulators [dt][et]
  float ksumAcc[2] = {0.f, 0.f};  // per-lane partial ksum (fixed e per nt)

  for (int t = 0; t < 4; ++t) {
    __syncthreads();  // previous tile fully consumed Xs
    // --- write staged regs -> LDS (loads were issued last iteration) ---
#pragma unroll
    for (int i = 0; i < 8; ++i) {
      const int flat = tid + i * 256;
      const int row = flat >> 5;
      const int c4  = (flat & 31) * 4;
      bf16x4 b4;
      b4[0] = (__bf16)xst[i].x; b4[1] = (__bf16)xst[i].y;
      b4[2] = (__bf16)xst[i].z; b4[3] = (__bf16)xst[i].w;
      *(bf16x4*)(&Xs[row * 136 + c4]) = b4;
    }
    // --- issue next tile's loads; they stay in flight across compute ---
    if (t < 3) {
      const float* Xn = Xc + (t + 1) * 64 * 128;
#pragma unroll
      for (int i = 0; i < 8; ++i) {
        const int flat = tid + i * 256;
        xst[i] = *(const float4*)(Xn + (flat >> 5) * 128 + (flat & 31) * 4);
      }
    }
    __syncthreads();  // Xs ready

    // --- K & V projections, orientation 1: D[tok][e] = X @ W ---
#pragma unroll
    for (int mt = 0; mt < 4; ++mt) {
      f32x4 aK[2] = {}, aV[2] = {};
#pragma unroll
      for (int kk = 0; kk < 4; ++kk) {
        const bf16x8 ax = *(const bf16x8*)(&Xs[(mt * 16 + l15) * 136 + kk * 32 + quad * 8]);
        aK[0] = mfma16(ax, wkF[0][kk], aK[0]);
        aK[1] = mfma16(ax, wkF[1][kk], aK[1]);
        aV[0] = mfma16(ax, wvF[0][kk], aV[0]);
        aV[1] = mfma16(ax, wvF[1][kk], aV[1]);
      }
      // epilogue: bias (+ elu+1 for K); write transposed to Kt/Vt.
#pragma unroll
      for (int nt = 0; nt < 2; ++nt) {
        const int e    = w * 32 + nt * 16 + l15;
        const int tokb = mt * 16 + quad * 4;
        bf16x4 kq, vq;
        float ks = 0.f;
#pragma unroll
        for (int r = 0; r < 4; ++r) {
          float kv = aK[nt][r] + bkr[nt];
          kv = (kv > 0.f) ? (kv + 1.f) : __expf(kv);   // elu(x)+1
          ks += kv;
          kq[r] = (__bf16)kv;
          vq[r] = (__bf16)(aV[nt][r] + bvr[nt]);
        }
        ksumAcc[nt] += ks;
        *(bf16x4*)(&Kt[e * 72 + tokb]) = kq;
        *(bf16x4*)(&Vt[e * 72 + tokb]) = vq;
      }
    }

    // --- KtV: wave w = head w. Kt/Vt rows are wave-private and DS ops of a
    // wave execute in order -> NO barrier needed here. ---
#pragma unroll
    for (int kk = 0; kk < 2; ++kk) {
      bf16x8 aF[2], bF[2];
#pragma unroll
      for (int dt = 0; dt < 2; ++dt)
        aF[dt] = *(const bf16x8*)(&Kt[(w * 32 + dt * 16 + l15) * 72 + kk * 32 + quad * 8]);
#pragma unroll
      for (int et = 0; et < 2; ++et)
        bF[et] = *(const bf16x8*)(&Vt[(w * 32 + et * 16 + l15) * 72 + kk * 32 + quad * 8]);
#pragma unroll
      for (int dt = 0; dt < 2; ++dt)
#pragma unroll
        for (int et = 0; et < 2; ++et)
          accT[dt][et] = mfma16(aF[dt], bF[et], accT[dt][et]);
    }
  }

  // --- flush partials: ktv[s][h][d][e], ksum[s][e] (fp32 atomics) ---
  float* ktvH = ktvWs + ((size_t)s * 4 + w) * 1024;
#pragma unroll
  for (int dt = 0; dt < 2; ++dt)
#pragma unroll
    for (int et = 0; et < 2; ++et)
#pragma unroll
      for (int r = 0; r < 4; ++r)
        atomicAdd(&ktvH[(dt * 16 + quad * 4 + r) * 32 + et * 16 + l15], accT[dt][et][r]);

#pragma unroll
  for (int nt = 0; nt < 2; ++nt) {
    float v2 = ksumAcc[nt];
    v2 += __shfl_down(v2, 32);
    v2 += __shfl_down(v2, 16);
    if (quad == 0)
      atomicAdd(&ksumWs[s * 128 + w * 32 + nt * 16 + l15], v2);
  }
}

// ---------------------------------------------------------------------------
// Kernel B: per (seq, 256-token chunk): recompute Q from X (orientation 2,
// D[e][tok]); elu+1; Z computed fully in-register (each lane holds 8 of the
// 32 q*ksum terms; 2 shfl_xor finish the head-local dot -- no Zs LDS, no
// barrier); GEMM2 (q @ KtV_h)*Z written in-place over the Q buffer
// (head-private columns, in-wave-ordered DS); GEMM3 out = A2 @ Wo + bo.
// LDS = Xs + QA2s = 34816 B -> 4 blocks/CU (50% occupancy).
// ---------------------------------------------------------------------------
__global__ __launch_bounds__(256, 4)
void attn_out_kernel(const float* __restrict__ X,
                     const float* __restrict__ Wq, const float* __restrict__ bq,
                     const float* __restrict__ ktvWs, const float* __restrict__ ksumWs,
                     const float* __restrict__ Wo, const float* __restrict__ bo,
                     float* __restrict__ Out)
{
  __shared__ __bf16 Xs[64 * 136];
  __shared__ __bf16 QA2s[64 * 136];   // holds Q, overwritten in place by A2

  const int tid  = threadIdx.x;
  const int lane = tid & 63;
  const int w    = tid >> 6;   // wave = head
  const int l15  = lane & 15;
  const int quad = lane >> 4;
  const int s     = blockIdx.x >> 3;
  const int chunk = blockIdx.x & 7;
  const float* Xc = X + ((size_t)s * 2048 + chunk * 256) * 128;
  float* OutC = Out + ((size_t)s * 2048 + chunk * 256) * 128;

  // weights / per-lane constants
  bf16x8 wqF[2][4], woF[2][4];
  float bqr[2][4], bor[2], ksumr[2][4];
#pragma unroll
  for (int nt = 0; nt < 2; ++nt) {
    const int n = w * 32 + nt * 16 + l15;
#pragma unroll
    for (int kk = 0; kk < 4; ++kk) {
      wqF[nt][kk] = loadWfrag(Wq, kk * 32 + quad * 8, n);   // A-operand: m=out-dim
      woF[nt][kk] = loadWfrag(Wo, kk * 32 + quad * 8, n);   // B-operand
    }
    bor[nt] = bo[n];
#pragma unroll
    for (int r = 0; r < 4; ++r) {
      bqr[nt][r]   = bq[w * 32 + nt * 16 + quad * 4 + r];
      ksumr[nt][r] = ksumWs[s * 128 + w * 32 + nt * 16 + quad * 4 + r];
    }
  }
  // KtV_h as orientation-2 A-fragments: A[e'][d] = KtV[h][d][e']
  const float* ktvH = ktvWs + ((size_t)s * 4 + w) * 1024;
  bf16x8 aKtv[2];
#pragma unroll
  for (int mt = 0; mt < 2; ++mt)
#pragma unroll
    for (int j = 0; j < 8; ++j)
      aKtv[mt][j] = (__bf16)ktvH[(quad * 8 + j) * 32 + mt * 16 + l15];

  for (int t = 0; t < 4; ++t) {
    const float* Xt = Xc + t * 64 * 128;
    __syncthreads();  // prev GEMM3 done with QA2s; Xs consumed
#pragma unroll
    for (int i = 0; i < 8; ++i) {
      const int flat = tid + i * 256;
      const int row = flat >> 5;
      const int c4  = (flat & 31) * 4;
      const float4 v = *(const float4*)(Xt + row * 128 + c4);
      bf16x4 b4;
      b4[0] = (__bf16)v.x; b4[1] = (__bf16)v.y;
      b4[2] = (__bf16)v.z; b4[3] = (__bf16)v.w;
      *(bf16x4*)(&Xs[row * 136 + c4]) = b4;
    }
    __syncthreads();  // Xs ready

    // --- Q projection (orientation 2: D[e][tok]) + in-register Z ---
    float zreg[4];
#pragma unroll
    for (int ntq = 0; ntq < 4; ++ntq) {
      f32x4 aQ[2] = {};
#pragma unroll
      for (int kk = 0; kk < 4; ++kk) {
        const bf16x8 bx = *(const bf16x8*)(&Xs[(ntq * 16 + l15) * 136 + kk * 32 + quad * 8]);
        aQ[0] = mfma16(wqF[0][kk], bx, aQ[0]);
        aQ[1] = mfma16(wqF[1][kk], bx, aQ[1]);
      }
      float dot = 0.f;
#pragma unroll
      for (int mt = 0; mt < 2; ++mt) {
        bf16x4 qq;
#pragma unroll
        for (int r = 0; r < 4; ++r) {
          float qv = aQ[mt][r] + bqr[mt][r];
          qv = (qv > 0.f) ? (qv + 1.f) : __expf(qv);
          dot += qv * ksumr[mt][r];
          qq[r] = (__bf16)qv;
        }
        *(bf16x4*)(&QA2s[(ntq * 16 + l15) * 136 + w * 32 + mt * 16 + quad * 4]) = qq;
      }
      // lane holds 8/32 of the head-local dot; quads hold the rest
      dot += __shfl_xor(dot, 16);
      dot += __shfl_xor(dot, 32);
      zreg[ntq] = 1.f / (dot + 1e-6f);
    }

    // --- GEMM2 (orientation 2): D[e'][tok] = KtV_h-frag @ Q^T, then *Z ---
    // Reads/writes only head-w columns of QA2s (wave-private, DS in-order).
#pragma unroll
    for (int ntq = 0; ntq < 4; ++ntq) {
      const bf16x8 bq8 = *(const bf16x8*)(&QA2s[(ntq * 16 + l15) * 136 + w * 32 + quad * 8]);
      f32x4 acc[2] = {};
      acc[0] = mfma16(aKtv[0], bq8, acc[0]);
      acc[1] = mfma16(aKtv[1], bq8, acc[1]);
      const float z = zreg[ntq];
#pragma unroll
      for (int mt = 0; mt < 2; ++mt) {
        bf16x4 a4;
#pragma unroll
        for (int r = 0; r < 4; ++r) a4[r] = (__bf16)(acc[mt][r] * z);
        *(bf16x4*)(&QA2s[(ntq * 16 + l15) * 136 + w * 32 + mt * 16 + quad * 4]) = a4;
      }
    }
    __syncthreads();  // A2 complete across all heads

    // --- GEMM3 (orientation 1): out[tok][n] = A2 @ Wo + bo ---
#pragma unroll
    for (int mt = 0; mt < 4; ++mt) {
      f32x4 acc[2] = {};
#pragma unroll
      for (int kk = 0; kk < 4; ++kk) {
        const bf16x8 aa = *(const bf16x8*)(&QA2s[(mt * 16 + l15) * 136 + kk * 32 + quad * 8]);
        acc[0] = mfma16(aa, woF[0][kk], acc[0]);
        acc[1] = mfma16(aa, woF[1][kk], acc[1]);
      }
      float* orow = OutC + (size_t)(t * 64 + mt * 16 + quad * 4) * 128;
#pragma unroll
      for (int nt = 0; nt < 2; ++nt) {
        const int n = w * 32 + nt * 16 + l15;
#pragma unroll
        for (int r = 0; r < 4; ++r)
          orow[(size_t)r * 128 + n] = acc[nt][r] + bor[nt];
      }
    }
  }
}

extern "C" void kernel_launch(void* const* d_in, const int* in_sizes, int n_in,
                              void* d_out, int out_size, void* d_ws, size_t ws_size,
                              hipStream_t stream) {
  const float* X  = (const float*)d_in[0];
  const float* Wq = (const float*)d_in[1];
  const float* bq = (const float*)d_in[2];
  const float* Wk = (const float*)d_in[3];
  const float* bk = (const float*)d_in[4];
  const float* Wv = (const float*)d_in[5];
  const float* bv = (const float*)d_in[6];
  const float* Wo = (const float*)d_in[7];
  const float* bo = (const float*)d_in[8];
  float* Out = (float*)d_out;

  // ws layout: ktv fp32 [128][4][32][32] | ksum fp32 [128][128]  (no Q buffer)
  const size_t KTV_BYTES  = (size_t)128 * 4 * 32 * 32 * 4;       // 2 MiB
  const size_t KSUM_BYTES = (size_t)128 * 128 * 4;               // 64 KiB
  float* ktvWs  = (float*)d_ws;
  float* ksumWs = (float*)((char*)d_ws + KTV_BYTES);

  hipMemsetAsync(d_ws, 0, KTV_BYTES + KSUM_BYTES, stream);

  kv_ktv_kernel<<<dim3(1024), dim3(256), 0, stream>>>(
      X, Wk, bk, Wv, bv, ktvWs, ksumWs);
  attn_out_kernel<<<dim3(1024), dim3(256), 0, stream>>>(
      X, Wq, bq, ktvWs, ksumWs, Wo, bo, Out);
}